// Round 5
// baseline (5258.814 us; speedup 1.0000x reference)
//
#include <hip/hip_runtime.h>
#include <hip/hip_fp16.h>

// Problem constants: B=8, F=48, S=64, D=512, NH=8, L=4, DFF=2048, M=64, PERIOD=30

// ---------------- f16 dot2 helpers ----------------
typedef _Float16 h2 __attribute__((ext_vector_type(2)));
__device__ inline h2 u2h(unsigned u){ union{unsigned u; h2 h;} c; c.u=u; return c.h; }
#if __has_builtin(__builtin_amdgcn_fdot2)
__device__ inline float FDOT2(h2 a, h2 b, float c){ return __builtin_amdgcn_fdot2(a, b, c, false); }
#else
__device__ inline float FDOT2(h2 a, h2 b, float c){
  return fmaf((float)a.y, (float)b.y, fmaf((float)a.x, (float)b.x, c));
}
#endif

__device__ inline float aload(const float* p){
  return __hip_atomic_load(p, __ATOMIC_RELAXED, __HIP_MEMORY_SCOPE_AGENT);
}
__device__ inline void astore(float* p, float v){
  __hip_atomic_store(p, v, __ATOMIC_RELAXED, __HIP_MEMORY_SCOPE_AGENT);
}

#define FD4(w,x) do{ a0=FDOT2(u2h((w).x),u2h((x).x),a0); a1=FDOT2(u2h((w).y),u2h((x).y),a1); \
                     a2=FDOT2(u2h((w).z),u2h((x).z),a2); a3=FDOT2(u2h((w).w),u2h((x).w),a3);}while(0)

// 128-f16 dot, all 16 uint4 streamed from global
__device__ inline float dot128s(const ushort* wrow, const ushort* xh){
  const uint4* w4=(const uint4*)wrow; const uint4* x4=(const uint4*)xh;
  float a0=0.f,a1=0.f,a2=0.f,a3=0.f;
  #pragma unroll
  for(int i=0;i<16;++i){ uint4 w=w4[i], x=x4[i]; FD4(w,x); }
  return (a0+a1)+(a2+a3);
}
// 128-f16 dot, all 16 uint4 from preloaded registers
__device__ inline float dot128p(const uint4 (&pw)[16], const ushort* xh){
  const uint4* x4=(const uint4*)xh;
  float a0=0.f,a1=0.f,a2=0.f,a3=0.f;
  #pragma unroll
  for(int i=0;i<16;++i){ uint4 w=pw[i], x=x4[i]; FD4(w,x); }
  return (a0+a1)+(a2+a3);
}
// 128-f16 dot, first 8 uint4 preloaded, rest streamed
__device__ inline float dot128p8(const uint4 (&pw)[8], const ushort* wrow, const ushort* xh){
  const uint4* w4=(const uint4*)wrow; const uint4* x4=(const uint4*)xh;
  float a0=0.f,a1=0.f,a2=0.f,a3=0.f;
  #pragma unroll
  for(int i=0;i<8;++i){ uint4 w=pw[i], x=x4[i]; FD4(w,x); }
  #pragma unroll
  for(int i=8;i<16;++i){ uint4 w=w4[i], x=x4[i]; FD4(w,x); }
  return (a0+a1)+(a2+a3);
}
// 32-f16 dot streamed (O projection slice)
__device__ inline float dot32s(const ushort* wrow, const ushort* xh){
  const uint4* w4=(const uint4*)wrow; const uint4* x4=(const uint4*)xh;
  float a0=0.f,a1=0.f,a2=0.f,a3=0.f;
  #pragma unroll
  for(int i=0;i<4;++i){ uint4 w=w4[i], x=x4[i]; FD4(w,x); }
  return (a0+a1)+(a2+a3);
}
// fp32 dots
__device__ inline float dot_f32(const float* wrow, const float* x, int n){
  const float4* w4 = (const float4*)wrow;
  float a0=0.f,a1=0.f,a2=0.f,a3=0.f;
  #pragma unroll 4
  for (int i=0; i<(n>>2); ++i){
    float4 w = w4[i]; const float* xp = x + i*4;
    a0 = fmaf(w.x, xp[0], a0); a1 = fmaf(w.y, xp[1], a1);
    a2 = fmaf(w.z, xp[2], a2); a3 = fmaf(w.w, xp[3], a3);
  }
  return (a0+a1)+(a2+a3);
}
// 64-f32 dot, first 8 float4 preloaded
__device__ inline float dot64f_p8(const float4 (&pw)[8], const float* wrow, const float* x){
  const float4* w4=(const float4*)wrow;
  float a0=0.f,a1=0.f,a2=0.f,a3=0.f;
  #pragma unroll
  for(int i=0;i<8;++i){ float4 w=pw[i]; const float* xp=x+i*4;
    a0=fmaf(w.x,xp[0],a0); a1=fmaf(w.y,xp[1],a1); a2=fmaf(w.z,xp[2],a2); a3=fmaf(w.w,xp[3],a3);}
  #pragma unroll
  for(int i=8;i<16;++i){ float4 w=w4[i]; const float* xp=x+i*4;
    a0=fmaf(w.x,xp[0],a0); a1=fmaf(w.y,xp[1],a1); a2=fmaf(w.z,xp[2],a2); a3=fmaf(w.w,xp[3],a3);}
  return (a0+a1)+(a2+a3);
}

// padded-chunk index maps (bank-conflict-free lane-split reads)
#define XSP(e) (((e)>>6)*68 + ((e)&63))     // fp32: 8 chunks of 64, stride 68
#define XHP(e) (((e)>>7)*136 + ((e)&127))   // f16: 4 chunks of 128, stride 136

// ---------------- transpose (src R x C -> dst C x R) ----------------
__global__ void k_transpose(const float* __restrict__ src, float* __restrict__ dst, int R, int C){
  __shared__ float tile[32][33];
  int cb = blockIdx.x*32, rb = blockIdx.y*32;
  int tx = threadIdx.x, ty = threadIdx.y;   // blockDim (32,8)
  for (int i=ty; i<32; i+=8) tile[i][tx] = src[(size_t)(rb+i)*C + cb+tx];
  __syncthreads();
  for (int i=ty; i<32; i+=8) dst[(size_t)(cb+i)*R + rb+tx] = tile[tx][i];
}

// cast fp32 -> f16 (same layout)
__global__ void k_casthf(const float* __restrict__ s, __half* __restrict__ d, int n){
  int i = blockIdx.x*256 + threadIdx.x;
  if (i < n) d[i] = __float2half(s[i]);
}

// ---------------- generic linear with optional z-batching ----------------
__global__ void k_linear(const float* __restrict__ A, int lda,
                         const float* __restrict__ Wt, int ldw,
                         const float* __restrict__ bias,
                         float* __restrict__ C, int ldc,
                         int O, int Din,
                         size_t aStr, size_t wStr, size_t bStr, size_t cStr){
  __shared__ float xs[8*1024];
  __shared__ float red[4096];
  int tid = threadIdx.x;
  int r0 = blockIdx.y*8;
  int z = blockIdx.z;
  const float* Az = A + (size_t)z*aStr;
  const float* Wz = Wt + (size_t)z*wStr;
  const float* Bz = bias ? bias + (size_t)z*bStr : nullptr;
  float* Cz = C + (size_t)z*cStr;
  for (int idx=tid; idx<8*Din; idx+=256){
    int ri = idx / Din, d = idx - ri*Din;
    xs[idx] = Az[(size_t)(r0+ri)*lda + d];
  }
  __syncthreads();
  int op = tid & 63, kp = tid >> 6;
  int o = blockIdx.x*128 + op*2;
  int dq = Din >> 2;
  float a0[8] = {0,0,0,0,0,0,0,0}, a1[8] = {0,0,0,0,0,0,0,0};
  for (int d = kp*dq; d < kp*dq+dq; ++d){
    float2 w = *reinterpret_cast<const float2*>(&Wz[(size_t)d*ldw + o]);
    #pragma unroll
    for (int ri=0; ri<8; ++ri){ float x = xs[ri*Din+d]; a0[ri] += x*w.x; a1[ri] += x*w.y; }
  }
  #pragma unroll
  for (int ri=0; ri<8; ++ri){
    red[((kp*64+op)*8+ri)*2]   = a0[ri];
    red[((kp*64+op)*8+ri)*2+1] = a1[ri];
  }
  __syncthreads();
  for (int idx = tid; idx < 1024; idx += 256){
    int ri = idx >> 7, oc = idx & 127;
    int opp = oc >> 1, c = oc & 1;
    float v = red[((0*64+opp)*8+ri)*2 + c] + red[((1*64+opp)*8+ri)*2 + c]
            + red[((2*64+opp)*8+ri)*2 + c] + red[((3*64+opp)*8+ri)*2 + c];
    int oo = blockIdx.x*128 + oc;
    if (Bz) v += Bz[oo];
    Cz[(size_t)(r0+ri)*ldc + oo] = v;
  }
}

// ---------------- PE table ----------------
__global__ void k_pe(float* __restrict__ pe){
  int idx = blockIdx.x*256 + threadIdx.x;  // 48*512
  int t = idx >> 9, d = idx & 511;
  int p = t % 30;
  int i2 = d & ~1;
  float div = __expf(-(float)i2 * (9.210340371976184f/512.f));
  float ang = (float)p * div;
  pe[idx] = (d & 1) ? cosf(ang) : sinf(ang);
}

// ---------------- sel attention (nh=1) ----------------
__global__ void k_sel_attn(const float* __restrict__ qh, const float* __restrict__ kh,
                           const float* __restrict__ vh, float* __restrict__ o){
  int bf = blockIdx.x;           // b*48+f
  int b  = bf / 48;
  int tid = threadIdx.x;
  __shared__ float qs[512];
  __shared__ float ps[64];
  qs[tid] = qh[(size_t)bf*512 + tid];
  qs[tid+256] = qh[(size_t)bf*512 + tid + 256];
  __syncthreads();
  if (tid < 64){
    const float* kr = kh + (size_t)(b*64+tid)*512;
    float a = 0.f;
    for (int d=0; d<512; ++d) a += qs[d]*kr[d];
    ps[tid] = a * 0.04419417382415922f;
  }
  __syncthreads();
  if (tid == 0){
    float m = -1e30f;
    for (int j=0;j<64;++j) m = fmaxf(m, ps[j]);
    float s = 0.f;
    for (int j=0;j<64;++j){ float e = __expf(ps[j]-m); ps[j]=e; s+=e; }
    float iv = 1.f/s;
    for (int j=0;j<64;++j) ps[j] *= iv;
  }
  __syncthreads();
  float a0=0.f, a1=0.f;
  for (int j=0;j<64;++j){
    const float* vr = vh + (size_t)(b*64+j)*512;
    float pj = ps[j];
    a0 += pj*vr[tid]; a1 += pj*vr[tid+256];
  }
  o[(size_t)bf*512+tid] = a0;
  o[(size_t)bf*512+tid+256] = a1;
}

// ---------------- tiny glue ----------------
__global__ void k_cat_tail(const float* __restrict__ sel, float* __restrict__ cat){
  int idx = blockIdx.x*256 + threadIdx.x;  // 8*512
  int b = idx >> 9, d = idx & 511;
  cat[b*1024 + 512 + d] = sel[(size_t)(b*48)*512 + d];
}
__global__ void k_add_style(const float* __restrict__ embt, const float* __restrict__ style,
                            float* __restrict__ emb){
  int idx = blockIdx.x*256 + threadIdx.x;  // 8*512 -> emb slot t=0
  emb[idx] = embt[idx] + style[idx];
}

// ---------------- persistent decode kernel ----------------
// 128 blocks x 512 threads (8 waves, 2/SIMD; 1 WG/CU, all co-resident).
// One batch per 16 WGs; role=(i&7)*2+((i>>3)&1) keeps per-XCD weight slice
// ~3.4MB (L2-resident). Sync: per-stage relaxed agent counters, poll-then-
// load (R3 lesson: data load must ISSUE after counter observed complete).
// R5: bank-conflict-free padded LDS activation layouts + weight register
// preload issued before each wait (L2 streaming overlaps detect latency).
struct DP {
  unsigned* fl;        // counters: [b][t][stage 0..8] at stride 16 dwords
  float* z;            // [b][t][8 slots][512] accumulators (memset 0)
  float* emb;          // [t 0..48][b][512] (memset 0; slot0 from precompute)
  const ushort *Wqkv, *Wo, *Wf1, *Wf2;   // f16, original [out][in] layout
  const float *xa_c, *pe;
  const float *sa_in_b, *sa_out_b, *ff1_b, *ff2_b;
  const float *mmr_w, *mmr_b, *mm_w, *mm_b, *se_w, *se_b;
  const float *ln_g, *ln_b, *style, *sel;
  float* dec_out;
};

__launch_bounds__(512, 2)
__global__ void k_decode(DP p){
  const int tid = threadIdx.x;
  const int i = blockIdx.x;
  const int role = ((i & 7) << 1) | ((i >> 3) & 1);
  const int b = i >> 4;
  const int h = role >> 1, half = role & 1;
  const float slope = exp2f(-(float)(h+1));

  __shared__ float kc[4*48*65];   // K cache fp32, pad 65 (49.9 KB)
  __shared__ float vs[4*48*64];   // V cache fp32 (49.2 KB)
  __shared__ float xsp[8*68];     // padded fp32 x (residual + tail mmr)
  __shared__ float red[512];
  __shared__ float qs[64], ps[64], d64[64];
  __shared__ float nsp[8*68];     // padded mm output
  __shared__ float selp[8*68];    // padded sel row (staged at l==3)
  __shared__ float lnred[16];
  __shared__ __align__(16) __half xhp[4*136];  // padded f16 x
  __shared__ __align__(16) __half anh[64];
  __shared__ __align__(16) __half hsh[128];

  unsigned* flb = p.fl + (size_t)b*48*9*16;
  float* zb = p.z + (size_t)b*48*8*512;

  auto waitz = [&](int t, int s, const float* src)->float{
    const unsigned* c = flb + (size_t)(t*9+s)*16;
    while (__hip_atomic_load(c, __ATOMIC_RELAXED, __HIP_MEMORY_SCOPE_AGENT) < 16u)
      __builtin_amdgcn_s_sleep(1);
    return aload(src + tid);
  };
  auto post = [&](int t, int s){
    __syncthreads();   // all waves drain vmcnt (atomics acked) at barrier
    if (tid == 0)
      __hip_atomic_fetch_add(flb + (size_t)(t*9+s)*16, 1u,
                             __ATOMIC_RELAXED, __HIP_MEMORY_SCOPE_AGENT);
  };
  // LN over 512, 1 elem/thread; optional padded stores.
  auto lnorm = [&](float v, const float* g, const float* bb,
                   bool toXs, bool toXh)->float{
    float s = v, q = v*v;
    #pragma unroll
    for (int off=32; off>0; off>>=1){ s += __shfl_xor(s, off, 64); q += __shfl_xor(q, off, 64); }
    if ((tid & 63) == 0){ lnred[tid>>6] = s; lnred[8+(tid>>6)] = q; }
    __syncthreads();
    s = 0.f; q = 0.f;
    #pragma unroll
    for (int w=0; w<8; ++w){ s += lnred[w]; q += lnred[8+w]; }
    float mu = s * (1.f/512.f);
    float rs = rsqrtf(q*(1.f/512.f) - mu*mu + 1e-5f);
    float r = (v-mu)*rs*g[tid] + bb[tid];
    if (toXs) xsp[XSP(tid)] = r;
    if (toXh) xhp[XHP(tid)] = __float2half(r);
    __syncthreads();
    return r;
  };

  for (int t=0; t<48; ++t){
    for (int l=0; l<4; ++l){
      // prefetch cross-attn constant (cold HBM) before any waiting
      const float* xac = p.xa_c + ((size_t)l*384 + b*48 + t)*512;
      float xa = xac[tid];
      // stage sel row for the tail (overlaps whole layer-3 with its load)
      if (l == 3) selp[XSP(tid)] = p.sel[((size_t)b*48+t)*512 + tid];

      // preload this thread's QKV weight slice (first 128 of 256) so the
      // L2 streaming overlaps the sync wait
      uint4 wq[16];
      const ushort* wqbase = nullptr;
      if (tid < 384){
        int row = tid >> 1, piece = tid & 1;
        int sec = row >> 6, dch = row & 63;
        int wrow = sec*512 + h*64 + dch;
        wqbase = p.Wqkv + ((size_t)l*1536 + wrow)*512 + piece*256;
        const uint4* w4 = (const uint4*)wqbase;
        #pragma unroll
        for (int k=0; k<16; ++k) wq[k] = w4[k];
      }

      // ===== stage A: x prep + QKV (own head) + attention + O-partial =====
      if (l == 0){
        float pe0 = p.pe[t*512+tid];             // prefetch
        float e;
        if (t > 0) e = waitz(t-1, 8, p.emb + ((size_t)t*8+b)*512);
        else       e = aload(p.emb + ((size_t)t*8+b)*512 + tid);
        float x = e + pe0;
        xsp[XSP(tid)] = x; xhp[XHP(tid)] = __float2half(x);
        __syncthreads();
      } else {
        float z = waitz(t, (l-1)*2+1, zb + ((size_t)t*8 + (l-1)*2+1)*512);
        lnorm(z, p.ln_g + ((l-1)*3+2)*512, p.ln_b + ((l-1)*3+2)*512, true, true);
      }
      // QKV: 192 rows x 2-lane split; each piece = 256 elems = 2 padded chunks
      if (tid < 384){
        int row = tid >> 1, piece = tid & 1;
        int sec = row >> 6, dch = row & 63;
        int wrow = sec*512 + h*64 + dch;
        float acc = dot128p(wq, (const ushort*)(xhp + (2*piece)*136))
                  + dot128s((const ushort*)wqbase + 128,
                            (const ushort*)(xhp + (2*piece+1)*136));
        acc += __shfl_xor(acc, 1, 64);
        if (piece == 0){
          acc += p.sa_in_b[l*1536+wrow];
          if (sec == 0) qs[dch] = acc;
          else if (sec == 1) kc[(l*48+t)*65 + dch] = acc;
          else vs[(l*48+t)*64 + dch] = acc;
        }
      }
      __syncthreads();
      // scores + softmax (wave 0)
      if (tid < 64){
        float sc = -1e30f;
        if (tid <= t){
          float a = 0.f;
          const float* kr = &kc[(l*48+tid)*65];
          #pragma unroll
          for (int d=0; d<64; ++d) a = fmaf(qs[d], kr[d], a);
          sc = a*0.125f - ((t-tid) >= 30 ? slope : 0.f);
        }
        float m = sc;
        #pragma unroll
        for (int off=32; off>0; off>>=1) m = fmaxf(m, __shfl_xor(m, off, 64));
        float e = (tid <= t) ? __expf(sc-m) : 0.f;
        float s = e;
        #pragma unroll
        for (int off=32; off>0; off>>=1) s += __shfl_xor(s, off, 64);
        ps[tid] = e / s;
      }
      __syncthreads();
      // PV: d = tid&63, j-eighth = tid>>6 (6 js each)
      {
        int d = tid & 63, jq = tid >> 6;
        float a = 0.f;
        for (int j=jq*6; j<jq*6+6; ++j)
          if (j <= t) a = fmaf(ps[j], vs[(l*48+j)*64 + d], a);
        red[tid] = a;
      }
      __syncthreads();
      if (tid < 64){
        float a = red[tid]+red[64+tid]+red[128+tid]+red[192+tid]
                + red[256+tid]+red[320+tid]+red[384+tid]+red[448+tid];
        anh[tid] = __float2half(a);
      }
      __syncthreads();
      // O-partial: 256 outputs (this half) x 2-lane split (32-dots)
      {
        int oi = tid >> 1, piece = tid & 1;
        int o = half*256 + oi;
        float acc = dot32s((const ushort*)(p.Wo + (((size_t)l*512+o)*512 + h*64) + piece*32),
                           (const ushort*)anh + piece*32);
        acc += __shfl_xor(acc, 1, 64);
        if (piece == 0){
          if (h == 0) acc += xsp[XSP(o)] + p.sa_out_b[l*512+o];  // residual+bias once
          unsafeAtomicAdd(zb + ((size_t)t*8 + l*2)*512 + o, acc);
        }
      }
      // preload FF1/FF2 weight slices before posting (stream during wait)
      uint4 wf1[8], wf2[8];
      {
        int row = tid >> 2, piece = tid & 3;
        const uint4* w4 = (const uint4*)(p.Wf1 + ((size_t)l*2048 + role*128 + row)*512 + piece*128);
        #pragma unroll
        for (int k=0; k<8; ++k) wf1[k] = w4[k];
        const uint4* w42 = (const uint4*)(p.Wf2 + ((size_t)l*512 + tid)*2048 + role*128);
        #pragma unroll
        for (int k=0; k<8; ++k) wf2[k] = w42[k];
      }
      post(t, l*2);

      // ===== stage B: LN + cross-const + LN + FF1 slice + FF2 partial =====
      float r;   // u2 (this thread's elem) for FF2 residual
      {
        float z = waitz(t, l*2, zb + ((size_t)t*8 + l*2)*512);
        float w = lnorm(z, p.ln_g + (l*3)*512, p.ln_b + (l*3)*512, false, false);
        float u = w + xa;
        r = lnorm(u, p.ln_g + (l*3+1)*512, p.ln_b + (l*3+1)*512, false, true);
      }
      // FF1: 128 rows x 4-lane split (128-dot = 1 padded chunk each)
      {
        int row = tid >> 2, piece = tid & 3;
        float a = dot128p8(wf1,
                           (const ushort*)(p.Wf1 + ((size_t)l*2048 + role*128 + row)*512 + piece*128),
                           (const ushort*)(xhp + piece*136));
        a += __shfl_xor(a, 1, 64);
        a += __shfl_xor(a, 2, 64);
        if (piece == 0)
          hsh[row] = __float2half(fmaxf(a + p.ff1_b[l*2048 + role*128 + row], 0.f));
      }
      __syncthreads();
      // FF2: 512 outputs x dot-128 over this role's hidden slice
      {
        float a0 = dot128p8(wf2,
                            (const ushort*)(p.Wf2 + ((size_t)l*512 + tid)*2048 + role*128),
                            (const ushort*)hsh);
        if (role == 0) a0 += r + p.ff2_b[l*512+tid];
        unsafeAtomicAdd(zb + ((size_t)t*8 + l*2+1)*512 + tid, a0);
      }
      post(t, l*2+1);
    } // layers

    // ===== tail: LN + mmr -> dec_out, mm -> new, se -> next emb =====
    // preload mmr weight slice (streams during the wait)
    float4 wm[8];
    {
      int o8 = tid >> 3, p8 = tid & 7;
      const float4* w4 = (const float4*)(p.mmr_w + (size_t)o8*512 + p8*64);
      #pragma unroll
      for (int k=0; k<8; ++k) wm[k] = w4[k];
    }
    {
      float z = waitz(t, 7, zb + ((size_t)t*8 + 7)*512);
      lnorm(z, p.ln_g + 11*512, p.ln_b + 11*512, true, false);
    }
    // mmr: 64 outs x 8-lane split (64-dots fp32, padded chunks)
    {
      int o8 = tid >> 3, p8 = tid & 7;
      float a = dot64f_p8(wm, p.mmr_w + (size_t)o8*512 + p8*64, xsp + p8*68);
      a += __shfl_xor(a, 1, 64);
      a += __shfl_xor(a, 2, 64);
      a += __shfl_xor(a, 4, 64);
      if (p8 == 0) d64[o8] = a + p.mmr_b[o8];
    }
    __syncthreads();
    if (role == 0 && tid < 64) p.dec_out[((size_t)b*48+t)*64 + tid] = d64[tid];
    // mm: 512 outs x dot-64 fp32 (d64 broadcast reads)
    nsp[XSP(tid)] = dot_f32(p.mm_w + (size_t)tid*64, d64, 64) + p.mm_b[tid];
    __syncthreads();
    // se: 32 outs (this role) x 16-lane split over concat[ns|sel] (padded)
    {
      int o5 = tid >> 4, p16 = tid & 15;
      int o = role*32 + o5;
      const float* xsrc = (p16 < 8) ? (nsp + p16*68) : (selp + (p16-8)*68);
      float acc = dot_f32(p.se_w + (size_t)o*1024 + p16*64, xsrc, 64);
      acc += __shfl_xor(acc, 1, 64);
      acc += __shfl_xor(acc, 2, 64);
      acc += __shfl_xor(acc, 4, 64);
      acc += __shfl_xor(acc, 8, 64);
      if (p16 == 0){
        acc += p.se_b[o] + p.style[(size_t)b*512+o];
        astore(p.emb + ((size_t)(t+1)*8+b)*512 + o, acc);
      }
    }
    post(t, 8);
  } // t
}

// ---------------- host ----------------
extern "C" void kernel_launch(void* const* d_in, const int* in_sizes, int n_in,
                              void* d_out, int out_size, void* d_ws, size_t ws_size,
                              hipStream_t stream){
  (void)in_sizes; (void)n_in; (void)out_size; (void)ws_size;
  const float* content = (const float*)d_in[0];
  const float* style   = (const float*)d_in[1];
  const float* shid    = (const float*)d_in[2];
  const float* init_st = (const float*)d_in[3];
  const float* ca_in_w = (const float*)d_in[4];
  const float* ca_in_b = (const float*)d_in[5];
  const float* ca_out_w= (const float*)d_in[6];
  const float* ca_out_b= (const float*)d_in[7];
  const float* se_w    = (const float*)d_in[8];
  const float* se_b    = (const float*)d_in[9];
  const float* mm_w    = (const float*)d_in[10];
  const float* mm_b    = (const float*)d_in[11];
  const float* mmr_w   = (const float*)d_in[12];
  const float* mmr_b   = (const float*)d_in[13];
  const float* sa_in_w = (const float*)d_in[14];
  const float* sa_in_b = (const float*)d_in[15];
  const float* sa_out_w= (const float*)d_in[16];
  const float* sa_out_b= (const float*)d_in[17];
  const float* xa_in_w = (const float*)d_in[18];
  const float* xa_in_b = (const float*)d_in[19];
  const float* xa_out_w= (const float*)d_in[20];
  const float* xa_out_b= (const float*)d_in[21];
  const float* ff1_w   = (const float*)d_in[22];
  const float* ff1_b   = (const float*)d_in[23];
  const float* ff2_w   = (const float*)d_in[24];
  const float* ff2_b   = (const float*)d_in[25];
  const float* ln_g    = (const float*)d_in[26];
  const float* ln_b    = (const float*)d_in[27];

  float* out = (float*)d_out;
  float* dec_out = out;            // (8,48,64)
  float* sel = out + 8*48*64;      // (8,48,512)

  char* base = (char*)d_ws;
  size_t cur = 0;
  auto alloc = [&](size_t bytes)->char*{
    char* pt = base + cur;
    cur += (bytes + 255) & ~(size_t)255;
    return pt;
  };
  // --- contiguous zero-init region: counters | z accum | emb slots ---
  unsigned* fl  = (unsigned*)alloc((size_t)8*48*9*16*4);          // 221184 B
  float* zacc   = (float*)alloc((size_t)8*48*8*512*4);            // 6.29 MB
  float* emb    = (float*)alloc((size_t)49*8*512*4);              // 0.80 MB
  size_t zero_span = cur;                                          // from fl
  // --- rest of workspace ---
  ushort* WqkvH = (ushort*)alloc((size_t)4*1536*512*2);
  ushort* WoH   = (ushort*)alloc((size_t)4*512*512*2);
  ushort* Wf1H  = (ushort*)alloc((size_t)4*2048*512*2);
  ushort* Wf2H  = (ushort*)alloc((size_t)4*512*2048*2);
  float* Wt_mm    = (float*)alloc((size_t)64*512*4);
  float* Wt_se    = (float*)alloc((size_t)1024*512*4);
  float* Wt_ca_in = (float*)alloc((size_t)512*1536*4);
  float* Wt_ca_out= (float*)alloc((size_t)512*512*4);
  float* Wt_xa_v  = (float*)alloc((size_t)4*512*512*4);
  float* Wt_xa_o  = (float*)alloc((size_t)4*512*512*4);
  float* xa_c  = (float*)alloc((size_t)4*384*512*4);
  float* pe    = (float*)alloc((size_t)48*512*4);
  float* qh    = (float*)alloc((size_t)384*512*4);
  float* khb   = (float*)alloc((size_t)512*512*4);   // K then V: adjacent
  float* vhb   = (float*)alloc((size_t)512*512*4);
  float* attno = (float*)alloc((size_t)384*512*4);
  float* xtmp4 = (float*)alloc((size_t)4*384*512*4);
  float* catb  = (float*)alloc((size_t)8*1024*4);
  float* embt  = (float*)alloc((size_t)8*512*4);
  (void)vhb;

  hipMemsetAsync(fl, 0, zero_span, stream);

  dim3 tb(32,8);
  // f16 casts (original [out][in] layout, contiguous rows)
  k_casthf<<<(4*1536*512+255)/256, 256, 0, stream>>>(sa_in_w, (__half*)WqkvH, 4*1536*512);
  k_casthf<<<(4*512*512+255)/256, 256, 0, stream>>>(sa_out_w, (__half*)WoH,  4*512*512);
  k_casthf<<<(4*2048*512+255)/256, 256, 0, stream>>>(ff1_w,  (__half*)Wf1H, 4*2048*512);
  k_casthf<<<(4*512*2048+255)/256, 256, 0, stream>>>(ff2_w,  (__half*)Wf2H, 4*512*2048);
  // fp32 transposes for the precompute GEMMs
  for (int l=0; l<4; ++l){
    k_transpose<<<dim3(16,16), tb, 0, stream>>>(xa_in_w + (size_t)l*1536*512 + (size_t)1024*512, Wt_xa_v + (size_t)l*512*512, 512, 512);
    k_transpose<<<dim3(16,16), tb, 0, stream>>>(xa_out_w + (size_t)l*512*512, Wt_xa_o + (size_t)l*512*512, 512, 512);
  }
  k_transpose<<<dim3(16,48), tb, 0, stream>>>(ca_in_w,  Wt_ca_in, 1536, 512);
  k_transpose<<<dim3(16,16), tb, 0, stream>>>(ca_out_w, Wt_ca_out, 512, 512);
  k_transpose<<<dim3(32,16), tb, 0, stream>>>(se_w,  Wt_se, 512, 1024);
  k_transpose<<<dim3(2,16),  tb, 0, stream>>>(mm_w,  Wt_mm, 512, 64);

  k_pe<<<96, 256, 0, stream>>>(pe);

  // sel = MHA(content, style_hiddens, style_hiddens), nh=1
  k_linear<<<dim3(4,48), 256, 0, stream>>>(content, 512, Wt_ca_in, 1536, ca_in_b, qh, 512, 512, 512, 0,0,0,0);
  // K and V batched (z=0:K, z=1:V)
  k_linear<<<dim3(4,64,2), 256, 0, stream>>>(shid, 512, Wt_ca_in + 512, 1536, ca_in_b + 512, khb, 512, 512, 512,
                                             0, 512, 512, (size_t)512*512);
  k_sel_attn<<<384, 256, 0, stream>>>(qh, khb, vhb, attno);
  k_linear<<<dim3(4,48), 256, 0, stream>>>(attno, 512, Wt_ca_out, 512, ca_out_b, sel, 512, 512, 512, 0,0,0,0);

  // cross-attn constants (diagonal mask -> one-hot softmax), z-batched over l
  k_linear<<<dim3(4,48,4), 256, 0, stream>>>(content, 512, Wt_xa_v, 512, xa_in_b + 1024, xtmp4, 512, 512, 512,
                                             0, (size_t)512*512, 1536, (size_t)384*512);
  k_linear<<<dim3(4,48,4), 256, 0, stream>>>(xtmp4, 512, Wt_xa_o, 512, xa_out_b, xa_c, 512, 512, 512,
                                             (size_t)384*512, (size_t)512*512, 512, (size_t)384*512);

  // emb slot 0
  k_linear<<<dim3(4,1), 256, 0, stream>>>(init_st, 64, Wt_mm, 512, mm_b, catb, 1024, 512, 64, 0,0,0,0);
  k_cat_tail<<<16, 256, 0, stream>>>(sel, catb);
  k_linear<<<dim3(4,1), 256, 0, stream>>>(catb, 1024, Wt_se, 512, se_b, embt, 512, 512, 1024, 0,0,0,0);
  k_add_style<<<16, 256, 0, stream>>>(embt, style, emb);

  DP p;
  p.fl = fl; p.z = zacc; p.emb = emb;
  p.Wqkv = WqkvH; p.Wo = WoH; p.Wf1 = Wf1H; p.Wf2 = Wf2H;
  p.xa_c = xa_c; p.pe = pe;
  p.sa_in_b = sa_in_b; p.sa_out_b = sa_out_b; p.ff1_b = ff1_b; p.ff2_b = ff2_b;
  p.mmr_w = mmr_w; p.mmr_b = mmr_b; p.mm_w = mm_w; p.mm_b = mm_b;
  p.se_w = se_w; p.se_b = se_b; p.ln_g = ln_g; p.ln_b = ln_b;
  p.style = style; p.sel = sel; p.dec_out = dec_out;

  k_decode<<<dim3(128), dim3(512), 0, stream>>>(p);
}

// Round 6
// 5074.358 us; speedup vs baseline: 1.0364x; 1.0364x over previous
//
#include <hip/hip_runtime.h>
#include <hip/hip_fp16.h>

// Problem constants: B=8, F=48, S=64, D=512, NH=8, L=4, DFF=2048, M=64, PERIOD=30

// ---------------- f16 dot2 helpers ----------------
typedef _Float16 h2 __attribute__((ext_vector_type(2)));
__device__ inline h2 u2h(unsigned u){ union{unsigned u; h2 h;} c; c.u=u; return c.h; }
#if __has_builtin(__builtin_amdgcn_fdot2)
__device__ inline float FDOT2(h2 a, h2 b, float c){ return __builtin_amdgcn_fdot2(a, b, c, false); }
#else
__device__ inline float FDOT2(h2 a, h2 b, float c){
  return fmaf((float)a.y, (float)b.y, fmaf((float)a.x, (float)b.x, c));
}
#endif

__device__ inline float aload(const float* p){
  return __hip_atomic_load(p, __ATOMIC_RELAXED, __HIP_MEMORY_SCOPE_AGENT);
}
__device__ inline void astore(float* p, float v){
  __hip_atomic_store(p, v, __ATOMIC_RELAXED, __HIP_MEMORY_SCOPE_AGENT);
}

#define FD4(w,x) do{ a0=FDOT2(u2h((w).x),u2h((x).x),a0); a1=FDOT2(u2h((w).y),u2h((x).y),a1); \
                     a2=FDOT2(u2h((w).z),u2h((x).z),a2); a3=FDOT2(u2h((w).w),u2h((x).w),a3);}while(0)

// 128-f16 dot, all 16 uint4 streamed from global
__device__ inline float dot128s(const ushort* wrow, const ushort* xh){
  const uint4* w4=(const uint4*)wrow; const uint4* x4=(const uint4*)xh;
  float a0=0.f,a1=0.f,a2=0.f,a3=0.f;
  #pragma unroll
  for(int i=0;i<16;++i){ uint4 w=w4[i], x=x4[i]; FD4(w,x); }
  return (a0+a1)+(a2+a3);
}
// 128-f16 dot, all 16 uint4 from preloaded registers
__device__ inline float dot128p(const uint4 (&pw)[16], const ushort* xh){
  const uint4* x4=(const uint4*)xh;
  float a0=0.f,a1=0.f,a2=0.f,a3=0.f;
  #pragma unroll
  for(int i=0;i<16;++i){ uint4 w=pw[i], x=x4[i]; FD4(w,x); }
  return (a0+a1)+(a2+a3);
}
// 128-f16 dot, first 8 uint4 preloaded, rest streamed
__device__ inline float dot128p8(const uint4 (&pw)[8], const ushort* wrow, const ushort* xh){
  const uint4* w4=(const uint4*)wrow; const uint4* x4=(const uint4*)xh;
  float a0=0.f,a1=0.f,a2=0.f,a3=0.f;
  #pragma unroll
  for(int i=0;i<8;++i){ uint4 w=pw[i], x=x4[i]; FD4(w,x); }
  #pragma unroll
  for(int i=8;i<16;++i){ uint4 w=w4[i], x=x4[i]; FD4(w,x); }
  return (a0+a1)+(a2+a3);
}
// 32-f16 dot streamed (O projection slice)
__device__ inline float dot32s(const ushort* wrow, const ushort* xh){
  const uint4* w4=(const uint4*)wrow; const uint4* x4=(const uint4*)xh;
  float a0=0.f,a1=0.f,a2=0.f,a3=0.f;
  #pragma unroll
  for(int i=0;i<4;++i){ uint4 w=w4[i], x=x4[i]; FD4(w,x); }
  return (a0+a1)+(a2+a3);
}
// fp32 dots
__device__ inline float dot_f32(const float* wrow, const float* x, int n){
  const float4* w4 = (const float4*)wrow;
  float a0=0.f,a1=0.f,a2=0.f,a3=0.f;
  #pragma unroll 4
  for (int i=0; i<(n>>2); ++i){
    float4 w = w4[i]; const float* xp = x + i*4;
    a0 = fmaf(w.x, xp[0], a0); a1 = fmaf(w.y, xp[1], a1);
    a2 = fmaf(w.z, xp[2], a2); a3 = fmaf(w.w, xp[3], a3);
  }
  return (a0+a1)+(a2+a3);
}
// 64-f32 dot, first 8 float4 preloaded
__device__ inline float dot64f_p8(const float4 (&pw)[8], const float* wrow, const float* x){
  const float4* w4=(const float4*)wrow;
  float a0=0.f,a1=0.f,a2=0.f,a3=0.f;
  #pragma unroll
  for(int i=0;i<8;++i){ float4 w=pw[i]; const float* xp=x+i*4;
    a0=fmaf(w.x,xp[0],a0); a1=fmaf(w.y,xp[1],a1); a2=fmaf(w.z,xp[2],a2); a3=fmaf(w.w,xp[3],a3);}
  #pragma unroll
  for(int i=8;i<16;++i){ float4 w=w4[i]; const float* xp=x+i*4;
    a0=fmaf(w.x,xp[0],a0); a1=fmaf(w.y,xp[1],a1); a2=fmaf(w.z,xp[2],a2); a3=fmaf(w.w,xp[3],a3);}
  return (a0+a1)+(a2+a3);
}

// padded-chunk index maps (bank-conflict-free lane-split reads)
#define XSP(e) (((e)>>6)*68 + ((e)&63))     // fp32: 8 chunks of 64, stride 68
#define XHP(e) (((e)>>7)*136 + ((e)&127))   // f16: 4 chunks of 128, stride 136

// ---------------- transpose (src R x C -> dst C x R) ----------------
__global__ void k_transpose(const float* __restrict__ src, float* __restrict__ dst, int R, int C){
  __shared__ float tile[32][33];
  int cb = blockIdx.x*32, rb = blockIdx.y*32;
  int tx = threadIdx.x, ty = threadIdx.y;   // blockDim (32,8)
  for (int i=ty; i<32; i+=8) tile[i][tx] = src[(size_t)(rb+i)*C + cb+tx];
  __syncthreads();
  for (int i=ty; i<32; i+=8) dst[(size_t)(cb+i)*R + rb+tx] = tile[tx][i];
}

// cast fp32 -> f16 (same layout)
__global__ void k_casthf(const float* __restrict__ s, __half* __restrict__ d, int n){
  int i = blockIdx.x*256 + threadIdx.x;
  if (i < n) d[i] = __float2half(s[i]);
}

// ---------------- generic linear with optional z-batching ----------------
__global__ void k_linear(const float* __restrict__ A, int lda,
                         const float* __restrict__ Wt, int ldw,
                         const float* __restrict__ bias,
                         float* __restrict__ C, int ldc,
                         int O, int Din,
                         size_t aStr, size_t wStr, size_t bStr, size_t cStr){
  __shared__ float xs[8*1024];
  __shared__ float red[4096];
  int tid = threadIdx.x;
  int r0 = blockIdx.y*8;
  int z = blockIdx.z;
  const float* Az = A + (size_t)z*aStr;
  const float* Wz = Wt + (size_t)z*wStr;
  const float* Bz = bias ? bias + (size_t)z*bStr : nullptr;
  float* Cz = C + (size_t)z*cStr;
  for (int idx=tid; idx<8*Din; idx+=256){
    int ri = idx / Din, d = idx - ri*Din;
    xs[idx] = Az[(size_t)(r0+ri)*lda + d];
  }
  __syncthreads();
  int op = tid & 63, kp = tid >> 6;
  int o = blockIdx.x*128 + op*2;
  int dq = Din >> 2;
  float a0[8] = {0,0,0,0,0,0,0,0}, a1[8] = {0,0,0,0,0,0,0,0};
  for (int d = kp*dq; d < kp*dq+dq; ++d){
    float2 w = *reinterpret_cast<const float2*>(&Wz[(size_t)d*ldw + o]);
    #pragma unroll
    for (int ri=0; ri<8; ++ri){ float x = xs[ri*Din+d]; a0[ri] += x*w.x; a1[ri] += x*w.y; }
  }
  #pragma unroll
  for (int ri=0; ri<8; ++ri){
    red[((kp*64+op)*8+ri)*2]   = a0[ri];
    red[((kp*64+op)*8+ri)*2+1] = a1[ri];
  }
  __syncthreads();
  for (int idx = tid; idx < 1024; idx += 256){
    int ri = idx >> 7, oc = idx & 127;
    int opp = oc >> 1, c = oc & 1;
    float v = red[((0*64+opp)*8+ri)*2 + c] + red[((1*64+opp)*8+ri)*2 + c]
            + red[((2*64+opp)*8+ri)*2 + c] + red[((3*64+opp)*8+ri)*2 + c];
    int oo = blockIdx.x*128 + oc;
    if (Bz) v += Bz[oo];
    Cz[(size_t)(r0+ri)*ldc + oo] = v;
  }
}

// ---------------- PE table ----------------
__global__ void k_pe(float* __restrict__ pe){
  int idx = blockIdx.x*256 + threadIdx.x;  // 48*512
  int t = idx >> 9, d = idx & 511;
  int p = t % 30;
  int i2 = d & ~1;
  float div = __expf(-(float)i2 * (9.210340371976184f/512.f));
  float ang = (float)p * div;
  pe[idx] = (d & 1) ? cosf(ang) : sinf(ang);
}

// ---------------- sel attention (nh=1) ----------------
__global__ void k_sel_attn(const float* __restrict__ qh, const float* __restrict__ kh,
                           const float* __restrict__ vh, float* __restrict__ o){
  int bf = blockIdx.x;           // b*48+f
  int b  = bf / 48;
  int tid = threadIdx.x;
  __shared__ float qs[512];
  __shared__ float ps[64];
  qs[tid] = qh[(size_t)bf*512 + tid];
  qs[tid+256] = qh[(size_t)bf*512 + tid + 256];
  __syncthreads();
  if (tid < 64){
    const float* kr = kh + (size_t)(b*64+tid)*512;
    float a = 0.f;
    for (int d=0; d<512; ++d) a += qs[d]*kr[d];
    ps[tid] = a * 0.04419417382415922f;
  }
  __syncthreads();
  if (tid == 0){
    float m = -1e30f;
    for (int j=0;j<64;++j) m = fmaxf(m, ps[j]);
    float s = 0.f;
    for (int j=0;j<64;++j){ float e = __expf(ps[j]-m); ps[j]=e; s+=e; }
    float iv = 1.f/s;
    for (int j=0;j<64;++j) ps[j] *= iv;
  }
  __syncthreads();
  float a0=0.f, a1=0.f;
  for (int j=0;j<64;++j){
    const float* vr = vh + (size_t)(b*64+j)*512;
    float pj = ps[j];
    a0 += pj*vr[tid]; a1 += pj*vr[tid+256];
  }
  o[(size_t)bf*512+tid] = a0;
  o[(size_t)bf*512+tid+256] = a1;
}

// ---------------- tiny glue ----------------
__global__ void k_cat_tail(const float* __restrict__ sel, float* __restrict__ cat){
  int idx = blockIdx.x*256 + threadIdx.x;  // 8*512
  int b = idx >> 9, d = idx & 511;
  cat[b*1024 + 512 + d] = sel[(size_t)(b*48)*512 + d];
}
__global__ void k_add_style(const float* __restrict__ embt, const float* __restrict__ style,
                            float* __restrict__ emb){
  int idx = blockIdx.x*256 + threadIdx.x;  // 8*512 -> emb slot t=0
  emb[idx] = embt[idx] + style[idx];
}

// ---------------- persistent decode kernel ----------------
// 128 blocks x 512 threads (8 waves, 2/SIMD; 1 WG/CU, all co-resident).
// One batch per 16 WGs; role=(i&7)*2+((i>>3)&1) keeps per-XCD weight slice
// ~3.4MB (L2-resident). Sync: per-stage relaxed agent counters, poll-then-
// load (R3 lesson: data load must ISSUE after counter observed complete).
// R6: (a) weight preloads strictly AFTER the flag store (R5 had FF preload
// before post -> its vmcnt drain delayed the flag by ~0.7us/stage);
// (b) single-thread polling: only tid 0 polls the counter line (was 8192
// threads across 16 WGs hammering one LLC line, queueing the producers'
// fetch_adds behind the read storm), then __syncthreads releases the WG.
struct DP {
  unsigned* fl;        // counters: [b][t][stage 0..8] at stride 16 dwords
  float* z;            // [b][t][8 slots][512] accumulators (memset 0)
  float* emb;          // [t 0..48][b][512] (memset 0; slot0 from precompute)
  const ushort *Wqkv, *Wo, *Wf1, *Wf2;   // f16, original [out][in] layout
  const float *xa_c, *pe;
  const float *sa_in_b, *sa_out_b, *ff1_b, *ff2_b;
  const float *mmr_w, *mmr_b, *mm_w, *mm_b, *se_w, *se_b;
  const float *ln_g, *ln_b, *style, *sel;
  float* dec_out;
};

__launch_bounds__(512, 2)
__global__ void k_decode(DP p){
  const int tid = threadIdx.x;
  const int i = blockIdx.x;
  const int role = ((i & 7) << 1) | ((i >> 3) & 1);
  const int b = i >> 4;
  const int h = role >> 1, half = role & 1;
  const float slope = exp2f(-(float)(h+1));

  __shared__ float kc[4*48*65];   // K cache fp32, pad 65 (49.9 KB)
  __shared__ float vs[4*48*64];   // V cache fp32 (49.2 KB)
  __shared__ float xsp[8*68];     // padded fp32 x (residual + tail mmr)
  __shared__ float red[512];
  __shared__ float qs[64], ps[64], d64[64];
  __shared__ float nsp[8*68];     // padded mm output
  __shared__ float selp[8*68];    // padded sel row (staged at l==3)
  __shared__ float lnred[16];
  __shared__ __align__(16) __half xhp[4*136];  // padded f16 x
  __shared__ __align__(16) __half anh[64];
  __shared__ __align__(16) __half hsh[128];

  unsigned* flb = p.fl + (size_t)b*48*9*16;
  float* zb = p.z + (size_t)b*48*8*512;

  // Single-thread poll to 16, barrier, THEN all threads load (load issued
  // after completion observed -> ordered after producers' drained adds).
  auto waitz = [&](int t, int s, const float* src)->float{
    const unsigned* c = flb + (size_t)(t*9+s)*16;
    if (tid == 0){
      while (__hip_atomic_load(c, __ATOMIC_RELAXED, __HIP_MEMORY_SCOPE_AGENT) < 16u)
        __builtin_amdgcn_s_sleep(1);
    }
    __syncthreads();
    return aload(src + tid);
  };
  auto post = [&](int t, int s){
    __syncthreads();   // all waves drain vmcnt (atomics acked) at barrier
    if (tid == 0)
      __hip_atomic_fetch_add(flb + (size_t)(t*9+s)*16, 1u,
                             __ATOMIC_RELAXED, __HIP_MEMORY_SCOPE_AGENT);
  };
  // LN over 512, 1 elem/thread; optional padded stores.
  auto lnorm = [&](float v, const float* g, const float* bb,
                   bool toXs, bool toXh)->float{
    float s = v, q = v*v;
    #pragma unroll
    for (int off=32; off>0; off>>=1){ s += __shfl_xor(s, off, 64); q += __shfl_xor(q, off, 64); }
    if ((tid & 63) == 0){ lnred[tid>>6] = s; lnred[8+(tid>>6)] = q; }
    __syncthreads();
    s = 0.f; q = 0.f;
    #pragma unroll
    for (int w=0; w<8; ++w){ s += lnred[w]; q += lnred[8+w]; }
    float mu = s * (1.f/512.f);
    float rs = rsqrtf(q*(1.f/512.f) - mu*mu + 1e-5f);
    float r = (v-mu)*rs*g[tid] + bb[tid];
    if (toXs) xsp[XSP(tid)] = r;
    if (toXh) xhp[XHP(tid)] = __float2half(r);
    __syncthreads();
    return r;
  };

  for (int t=0; t<48; ++t){
    for (int l=0; l<4; ++l){
      // prefetch cross-attn constant (cold HBM) before any waiting
      const float* xac = p.xa_c + ((size_t)l*384 + b*48 + t)*512;
      float xa = xac[tid];
      // stage sel row for the tail (overlaps whole layer-3 with its load)
      if (l == 3) selp[XSP(tid)] = p.sel[((size_t)b*48+t)*512 + tid];

      // preload this thread's QKV weight slice (first 128 of 256) so the
      // L2 streaming overlaps the sync wait (previous post already issued)
      uint4 wq[16];
      const ushort* wqbase = nullptr;
      if (tid < 384){
        int row = tid >> 1, piece = tid & 1;
        int sec = row >> 6, dch = row & 63;
        int wrow = sec*512 + h*64 + dch;
        wqbase = p.Wqkv + ((size_t)l*1536 + wrow)*512 + piece*256;
        const uint4* w4 = (const uint4*)wqbase;
        #pragma unroll
        for (int k=0; k<16; ++k) wq[k] = w4[k];
      }

      // ===== stage A: x prep + QKV (own head) + attention + O-partial =====
      if (l == 0){
        float pe0 = p.pe[t*512+tid];             // prefetch
        float e;
        if (t > 0) e = waitz(t-1, 8, p.emb + ((size_t)t*8+b)*512);
        else       e = aload(p.emb + ((size_t)t*8+b)*512 + tid);
        float x = e + pe0;
        xsp[XSP(tid)] = x; xhp[XHP(tid)] = __float2half(x);
        __syncthreads();
      } else {
        float z = waitz(t, (l-1)*2+1, zb + ((size_t)t*8 + (l-1)*2+1)*512);
        lnorm(z, p.ln_g + ((l-1)*3+2)*512, p.ln_b + ((l-1)*3+2)*512, true, true);
      }
      // QKV: 192 rows x 2-lane split; each piece = 256 elems = 2 padded chunks
      if (tid < 384){
        int row = tid >> 1, piece = tid & 1;
        int sec = row >> 6, dch = row & 63;
        int wrow = sec*512 + h*64 + dch;
        float acc = dot128p(wq, (const ushort*)(xhp + (2*piece)*136))
                  + dot128s((const ushort*)wqbase + 128,
                            (const ushort*)(xhp + (2*piece+1)*136));
        acc += __shfl_xor(acc, 1, 64);
        if (piece == 0){
          acc += p.sa_in_b[l*1536+wrow];
          if (sec == 0) qs[dch] = acc;
          else if (sec == 1) kc[(l*48+t)*65 + dch] = acc;
          else vs[(l*48+t)*64 + dch] = acc;
        }
      }
      __syncthreads();
      // scores + softmax (wave 0)
      if (tid < 64){
        float sc = -1e30f;
        if (tid <= t){
          float a = 0.f;
          const float* kr = &kc[(l*48+tid)*65];
          #pragma unroll
          for (int d=0; d<64; ++d) a = fmaf(qs[d], kr[d], a);
          sc = a*0.125f - ((t-tid) >= 30 ? slope : 0.f);
        }
        float m = sc;
        #pragma unroll
        for (int off=32; off>0; off>>=1) m = fmaxf(m, __shfl_xor(m, off, 64));
        float e = (tid <= t) ? __expf(sc-m) : 0.f;
        float s = e;
        #pragma unroll
        for (int off=32; off>0; off>>=1) s += __shfl_xor(s, off, 64);
        ps[tid] = e / s;
      }
      __syncthreads();
      // PV: d = tid&63, j-eighth = tid>>6 (6 js each)
      {
        int d = tid & 63, jq = tid >> 6;
        float a = 0.f;
        for (int j=jq*6; j<jq*6+6; ++j)
          if (j <= t) a = fmaf(ps[j], vs[(l*48+j)*64 + d], a);
        red[tid] = a;
      }
      __syncthreads();
      if (tid < 64){
        float a = red[tid]+red[64+tid]+red[128+tid]+red[192+tid]
                + red[256+tid]+red[320+tid]+red[384+tid]+red[448+tid];
        anh[tid] = __float2half(a);
      }
      __syncthreads();
      // O-partial: 256 outputs (this half) x 2-lane split (32-dots)
      {
        int oi = tid >> 1, piece = tid & 1;
        int o = half*256 + oi;
        float acc = dot32s((const ushort*)(p.Wo + (((size_t)l*512+o)*512 + h*64) + piece*32),
                           (const ushort*)anh + piece*32);
        acc += __shfl_xor(acc, 1, 64);
        if (piece == 0){
          if (h == 0) acc += xsp[XSP(o)] + p.sa_out_b[l*512+o];  // residual+bias once
          unsafeAtomicAdd(zb + ((size_t)t*8 + l*2)*512 + o, acc);
        }
      }
      post(t, l*2);

      // preload FF1/FF2 weight slices AFTER the flag (streams during wait)
      uint4 wf1[8], wf2[8];
      {
        int row = tid >> 2, piece = tid & 3;
        const uint4* w4 = (const uint4*)(p.Wf1 + ((size_t)l*2048 + role*128 + row)*512 + piece*128);
        #pragma unroll
        for (int k=0; k<8; ++k) wf1[k] = w4[k];
        const uint4* w42 = (const uint4*)(p.Wf2 + ((size_t)l*512 + tid)*2048 + role*128);
        #pragma unroll
        for (int k=0; k<8; ++k) wf2[k] = w42[k];
      }

      // ===== stage B: LN + cross-const + LN + FF1 slice + FF2 partial =====
      float r;   // u2 (this thread's elem) for FF2 residual
      {
        float z = waitz(t, l*2, zb + ((size_t)t*8 + l*2)*512);
        float w = lnorm(z, p.ln_g + (l*3)*512, p.ln_b + (l*3)*512, false, false);
        float u = w + xa;
        r = lnorm(u, p.ln_g + (l*3+1)*512, p.ln_b + (l*3+1)*512, false, true);
      }
      // FF1: 128 rows x 4-lane split (128-dot = 1 padded chunk each)
      {
        int row = tid >> 2, piece = tid & 3;
        float a = dot128p8(wf1,
                           (const ushort*)(p.Wf1 + ((size_t)l*2048 + role*128 + row)*512 + piece*128),
                           (const ushort*)(xhp + piece*136));
        a += __shfl_xor(a, 1, 64);
        a += __shfl_xor(a, 2, 64);
        if (piece == 0)
          hsh[row] = __float2half(fmaxf(a + p.ff1_b[l*2048 + role*128 + row], 0.f));
      }
      __syncthreads();
      // FF2: 512 outputs x dot-128 over this role's hidden slice
      {
        float a0 = dot128p8(wf2,
                            (const ushort*)(p.Wf2 + ((size_t)l*512 + tid)*2048 + role*128),
                            (const ushort*)hsh);
        if (role == 0) a0 += r + p.ff2_b[l*512+tid];
        unsafeAtomicAdd(zb + ((size_t)t*8 + l*2+1)*512 + tid, a0);
      }
      post(t, l*2+1);
    } // layers

    // ===== tail: LN + mmr -> dec_out, mm -> new, se -> next emb =====
    // preload mmr weight slice (after post(t,7); streams during the wait)
    float4 wm[8];
    {
      int o8 = tid >> 3, p8 = tid & 7;
      const float4* w4 = (const float4*)(p.mmr_w + (size_t)o8*512 + p8*64);
      #pragma unroll
      for (int k=0; k<8; ++k) wm[k] = w4[k];
    }
    {
      float z = waitz(t, 7, zb + ((size_t)t*8 + 7)*512);
      lnorm(z, p.ln_g + 11*512, p.ln_b + 11*512, true, false);
    }
    // mmr: 64 outs x 8-lane split (64-dots fp32, padded chunks)
    {
      int o8 = tid >> 3, p8 = tid & 7;
      float a = dot64f_p8(wm, p.mmr_w + (size_t)o8*512 + p8*64, xsp + p8*68);
      a += __shfl_xor(a, 1, 64);
      a += __shfl_xor(a, 2, 64);
      a += __shfl_xor(a, 4, 64);
      if (p8 == 0) d64[o8] = a + p.mmr_b[o8];
    }
    __syncthreads();
    if (role == 0 && tid < 64) p.dec_out[((size_t)b*48+t)*64 + tid] = d64[tid];
    // mm: 512 outs x dot-64 fp32 (d64 broadcast reads)
    nsp[XSP(tid)] = dot_f32(p.mm_w + (size_t)tid*64, d64, 64) + p.mm_b[tid];
    __syncthreads();
    // se: 32 outs (this role) x 16-lane split over concat[ns|sel] (padded)
    {
      int o5 = tid >> 4, p16 = tid & 15;
      int o = role*32 + o5;
      const float* xsrc = (p16 < 8) ? (nsp + p16*68) : (selp + (p16-8)*68);
      float acc = dot_f32(p.se_w + (size_t)o*1024 + p16*64, xsrc, 64);
      acc += __shfl_xor(acc, 1, 64);
      acc += __shfl_xor(acc, 2, 64);
      acc += __shfl_xor(acc, 4, 64);
      acc += __shfl_xor(acc, 8, 64);
      if (p16 == 0){
        acc += p.se_b[o] + p.style[(size_t)b*512+o];
        astore(p.emb + ((size_t)(t+1)*8+b)*512 + o, acc);
      }
    }
    post(t, 8);
  } // t
}

// ---------------- host ----------------
extern "C" void kernel_launch(void* const* d_in, const int* in_sizes, int n_in,
                              void* d_out, int out_size, void* d_ws, size_t ws_size,
                              hipStream_t stream){
  (void)in_sizes; (void)n_in; (void)out_size; (void)ws_size;
  const float* content = (const float*)d_in[0];
  const float* style   = (const float*)d_in[1];
  const float* shid    = (const float*)d_in[2];
  const float* init_st = (const float*)d_in[3];
  const float* ca_in_w = (const float*)d_in[4];
  const float* ca_in_b = (const float*)d_in[5];
  const float* ca_out_w= (const float*)d_in[6];
  const float* ca_out_b= (const float*)d_in[7];
  const float* se_w    = (const float*)d_in[8];
  const float* se_b    = (const float*)d_in[9];
  const float* mm_w    = (const float*)d_in[10];
  const float* mm_b    = (const float*)d_in[11];
  const float* mmr_w   = (const float*)d_in[12];
  const float* mmr_b   = (const float*)d_in[13];
  const float* sa_in_w = (const float*)d_in[14];
  const float* sa_in_b = (const float*)d_in[15];
  const float* sa_out_w= (const float*)d_in[16];
  const float* sa_out_b= (const float*)d_in[17];
  const float* xa_in_w = (const float*)d_in[18];
  const float* xa_in_b = (const float*)d_in[19];
  const float* xa_out_w= (const float*)d_in[20];
  const float* xa_out_b= (const float*)d_in[21];
  const float* ff1_w   = (const float*)d_in[22];
  const float* ff1_b   = (const float*)d_in[23];
  const float* ff2_w   = (const float*)d_in[24];
  const float* ff2_b   = (const float*)d_in[25];
  const float* ln_g    = (const float*)d_in[26];
  const float* ln_b    = (const float*)d_in[27];

  float* out = (float*)d_out;
  float* dec_out = out;            // (8,48,64)
  float* sel = out + 8*48*64;      // (8,48,512)

  char* base = (char*)d_ws;
  size_t cur = 0;
  auto alloc = [&](size_t bytes)->char*{
    char* pt = base + cur;
    cur += (bytes + 255) & ~(size_t)255;
    return pt;
  };
  // --- contiguous zero-init region: counters | z accum | emb slots ---
  unsigned* fl  = (unsigned*)alloc((size_t)8*48*9*16*4);          // 221184 B
  float* zacc   = (float*)alloc((size_t)8*48*8*512*4);            // 6.29 MB
  float* emb    = (float*)alloc((size_t)49*8*512*4);              // 0.80 MB
  size_t zero_span = cur;                                          // from fl
  // --- rest of workspace ---
  ushort* WqkvH = (ushort*)alloc((size_t)4*1536*512*2);
  ushort* WoH   = (ushort*)alloc((size_t)4*512*512*2);
  ushort* Wf1H  = (ushort*)alloc((size_t)4*2048*512*2);
  ushort* Wf2H  = (ushort*)alloc((size_t)4*512*2048*2);
  float* Wt_mm    = (float*)alloc((size_t)64*512*4);
  float* Wt_se    = (float*)alloc((size_t)1024*512*4);
  float* Wt_ca_in = (float*)alloc((size_t)512*1536*4);
  float* Wt_ca_out= (float*)alloc((size_t)512*512*4);
  float* Wt_xa_v  = (float*)alloc((size_t)4*512*512*4);
  float* Wt_xa_o  = (float*)alloc((size_t)4*512*512*4);
  float* xa_c  = (float*)alloc((size_t)4*384*512*4);
  float* pe    = (float*)alloc((size_t)48*512*4);
  float* qh    = (float*)alloc((size_t)384*512*4);
  float* khb   = (float*)alloc((size_t)512*512*4);   // K then V: adjacent
  float* vhb   = (float*)alloc((size_t)512*512*4);
  float* attno = (float*)alloc((size_t)384*512*4);
  float* xtmp4 = (float*)alloc((size_t)4*384*512*4);
  float* catb  = (float*)alloc((size_t)8*1024*4);
  float* embt  = (float*)alloc((size_t)8*512*4);
  (void)vhb;

  hipMemsetAsync(fl, 0, zero_span, stream);

  dim3 tb(32,8);
  // f16 casts (original [out][in] layout, contiguous rows)
  k_casthf<<<(4*1536*512+255)/256, 256, 0, stream>>>(sa_in_w, (__half*)WqkvH, 4*1536*512);
  k_casthf<<<(4*512*512+255)/256, 256, 0, stream>>>(sa_out_w, (__half*)WoH,  4*512*512);
  k_casthf<<<(4*2048*512+255)/256, 256, 0, stream>>>(ff1_w,  (__half*)Wf1H, 4*2048*512);
  k_casthf<<<(4*512*2048+255)/256, 256, 0, stream>>>(ff2_w,  (__half*)Wf2H, 4*512*2048);
  // fp32 transposes for the precompute GEMMs
  for (int l=0; l<4; ++l){
    k_transpose<<<dim3(16,16), tb, 0, stream>>>(xa_in_w + (size_t)l*1536*512 + (size_t)1024*512, Wt_xa_v + (size_t)l*512*512, 512, 512);
    k_transpose<<<dim3(16,16), tb, 0, stream>>>(xa_out_w + (size_t)l*512*512, Wt_xa_o + (size_t)l*512*512, 512, 512);
  }
  k_transpose<<<dim3(16,48), tb, 0, stream>>>(ca_in_w,  Wt_ca_in, 1536, 512);
  k_transpose<<<dim3(16,16), tb, 0, stream>>>(ca_out_w, Wt_ca_out, 512, 512);
  k_transpose<<<dim3(32,16), tb, 0, stream>>>(se_w,  Wt_se, 512, 1024);
  k_transpose<<<dim3(2,16),  tb, 0, stream>>>(mm_w,  Wt_mm, 512, 64);

  k_pe<<<96, 256, 0, stream>>>(pe);

  // sel = MHA(content, style_hiddens, style_hiddens), nh=1
  k_linear<<<dim3(4,48), 256, 0, stream>>>(content, 512, Wt_ca_in, 1536, ca_in_b, qh, 512, 512, 512, 0,0,0,0);
  // K and V batched (z=0:K, z=1:V)
  k_linear<<<dim3(4,64,2), 256, 0, stream>>>(shid, 512, Wt_ca_in + 512, 1536, ca_in_b + 512, khb, 512, 512, 512,
                                             0, 512, 512, (size_t)512*512);
  k_sel_attn<<<384, 256, 0, stream>>>(qh, khb, vhb, attno);
  k_linear<<<dim3(4,48), 256, 0, stream>>>(attno, 512, Wt_ca_out, 512, ca_out_b, sel, 512, 512, 512, 0,0,0,0);

  // cross-attn constants (diagonal mask -> one-hot softmax), z-batched over l
  k_linear<<<dim3(4,48,4), 256, 0, stream>>>(content, 512, Wt_xa_v, 512, xa_in_b + 1024, xtmp4, 512, 512, 512,
                                             0, (size_t)512*512, 1536, (size_t)384*512);
  k_linear<<<dim3(4,48,4), 256, 0, stream>>>(xtmp4, 512, Wt_xa_o, 512, xa_out_b, xa_c, 512, 512, 512,
                                             (size_t)384*512, (size_t)512*512, 512, (size_t)384*512);

  // emb slot 0
  k_linear<<<dim3(4,1), 256, 0, stream>>>(init_st, 64, Wt_mm, 512, mm_b, catb, 1024, 512, 64, 0,0,0,0);
  k_cat_tail<<<16, 256, 0, stream>>>(sel, catb);
  k_linear<<<dim3(4,1), 256, 0, stream>>>(catb, 1024, Wt_se, 512, se_b, embt, 512, 512, 1024, 0,0,0,0);
  k_add_style<<<16, 256, 0, stream>>>(embt, style, emb);

  DP p;
  p.fl = fl; p.z = zacc; p.emb = emb;
  p.Wqkv = WqkvH; p.Wo = WoH; p.Wf1 = Wf1H; p.Wf2 = Wf2H;
  p.xa_c = xa_c; p.pe = pe;
  p.sa_in_b = sa_in_b; p.sa_out_b = sa_out_b; p.ff1_b = ff1_b; p.ff2_b = ff2_b;
  p.mmr_w = mmr_w; p.mmr_b = mmr_b; p.mm_w = mm_w; p.mm_b = mm_b;
  p.se_w = se_w; p.se_b = se_b; p.ln_g = ln_g; p.ln_b = ln_b;
  p.style = style; p.sel = sel; p.dec_out = dec_out;

  k_decode<<<dim3(128), dim3(512), 0, stream>>>(p);
}